// Round 7
// baseline (295.531 us; speedup 1.0000x reference)
//
#include <hip/hip_runtime.h>
#include <stdint.h>

#define NB 256
#define NL 128
#define ND1 512
#define ND2 512

#define BI 128              // i-rows of W per LDS slab
#define NSL (ND1 / BI)      // 4 slabs
#define NKT (ND2 / 32)      // 16 k-steps of 32

typedef float float4_t __attribute__((ext_vector_type(4)));
typedef __bf16 bf16x8_t __attribute__((ext_vector_type(8)));
typedef unsigned short ushort8_t __attribute__((ext_vector_type(8)));

__device__ __forceinline__ unsigned short f2bf(float f) {
    unsigned int u = __float_as_uint(f);
    u += 0x7FFFu + ((u >> 16) & 1u);
    return (unsigned short)(u >> 16);
}

__device__ __forceinline__ ushort8_t pack8(float4_t lo, float4_t hi) {
    ushort8_t u;
    u[0] = f2bf(lo.x); u[1] = f2bf(lo.y); u[2] = f2bf(lo.z); u[3] = f2bf(lo.w);
    u[4] = f2bf(hi.x); u[5] = f2bf(hi.y); u[6] = f2bf(hi.z); u[7] = f2bf(hi.w);
    return u;
}

// out[b,l] = sum_ij t1[b,l,i] W[e,i,j] t2[b,l,j]
// Z = T2 x W^T. One block per batch. W streams through a 128 KB LDS slab
// (4 i-slabs of 128x512 bf16, XOR-swizzled chunks -> 0 bank conflicts, cf R6).
// A (t2) streams from global INSIDE the barrier-free k-loop with prefetch
// distance 4 (8 dwordx4/lane in flight); slab staging uses 8-deep bursts.
// Register budget kept < 128 (16 waves/CU) -- NO afrag cache (R6's spill).
__global__ __launch_bounds__(1024, 4) void pdot_kernel(
    const float* __restrict__ t1, const float* __restrict__ t2,
    const int* __restrict__ pidx, const float* __restrict__ wgt,
    float* __restrict__ out)
{
    __shared__ unsigned short sW[BI * ND2];   // 131072 B; chunk c of row r at c^(r&31)

    const int b  = blockIdx.x;
    const int t  = threadIdx.x;    // 0..1023
    const int wv = t >> 6;         // 0..15
    const int mg = wv >> 1;        // l-group: rows mg*16..+15
    const int ih = wv & 1;         // i-half within slab: cols ih*64..+63
    const int ln = t & 63;
    const int nh = ln & 15;
    const int qd = ln >> 4;

    const int e = pidx[b];
    const float* wp  = wgt + (size_t)e * (ND1 * ND2);
    const float* t1p = t1  + (size_t)b * (NL * ND1);
    // A-fragment source: t2[b, mg*16+nh, kt*32 + qd*8 .. +7]
    const float* aRow = t2 + (size_t)b * (NL * ND2) + (size_t)(mg * 16 + nh) * ND2 + qd * 8;

    // staging map: thread owns slab-row sr (0..127), chunks sc+8q (q=0..7); chunk = 8 floats -> 8 bf16
    const int sr  = t >> 3;
    const int sc  = t & 7;
    const int ssw = sr & 31;
    unsigned short* dstrow = &sW[sr * ND2];

    // B-fragment slab rows for this wave: r(ns) = ih*64 + ns*16 + nh
    int rrow[4], rsw[4];
    #pragma unroll
    for (int ns = 0; ns < 4; ++ns) {
        rrow[ns] = ih * 64 + ns * 16 + nh;
        rsw[ns]  = rrow[ns] & 31;
    }

    float4_t ps = {0.f, 0.f, 0.f, 0.f};   // running per-lane partials of out rows

    for (int s = 0; s < NSL; ++s) {
        if (s > 0) __syncthreads();        // protect sW from overwrite while others compute

        // ---- stage W slab s: two 8-deep bursts (8 dwordx4 in flight per lane)
        {
            const float* src = wp + (size_t)(s * BI + sr) * ND2;
            #pragma unroll
            for (int h = 0; h < 2; ++h) {
                float4_t wl[4][2];
                #pragma unroll
                for (int q = 0; q < 4; ++q) {
                    const int c = sc + 8 * (h * 4 + q);
                    wl[q][0] = *(const float4_t*)(src + c * 8);
                    wl[q][1] = *(const float4_t*)(src + c * 8 + 4);
                }
                #pragma unroll
                for (int q = 0; q < 4; ++q) {
                    const int c = sc + 8 * (h * 4 + q);
                    *(ushort8_t*)(dstrow + ((c ^ ssw) * 8)) = pack8(wl[q][0], wl[q][1]);
                }
            }
        }

        // ---- preload A prefetch regs (independent of LDS; in flight across barrier)
        float4_t ra[4][2];
        #pragma unroll
        for (int p = 0; p < 4; ++p) {
            ra[p][0] = *(const float4_t*)(aRow + p * 32);
            ra[p][1] = *(const float4_t*)(aRow + p * 32 + 4);
        }

        __syncthreads();

        // ---- barrier-free k-loop over 16 k-steps; distance-4 A prefetch
        float4_t acc[4];
        #pragma unroll
        for (int ns = 0; ns < 4; ++ns) { float4_t z = {0.f,0.f,0.f,0.f}; acc[ns] = z; }

        #pragma unroll
        for (int kt = 0; kt < NKT; ++kt) {
            bf16x8_t af = __builtin_bit_cast(bf16x8_t, pack8(ra[kt & 3][0], ra[kt & 3][1]));
            if (kt < NKT - 4) {
                ra[kt & 3][0] = *(const float4_t*)(aRow + (kt + 4) * 32);
                ra[kt & 3][1] = *(const float4_t*)(aRow + (kt + 4) * 32 + 4);
            }
            #pragma unroll
            for (int ns = 0; ns < 4; ++ns) {
                const int chunk = (kt * 4 + qd) ^ rsw[ns];
                bf16x8_t bfr = __builtin_bit_cast(bf16x8_t,
                    *(const ushort8_t*)(&sW[rrow[ns] * ND2 + chunk * 8]));
                acc[ns] = __builtin_amdgcn_mfma_f32_16x16x32_bf16(af, bfr, acc[ns], 0, 0, 0);
            }
        }

        // ---- fold epilogue for this slab: ps[r] += Z[l,i] * t1[l,i]
        // C/D: col(i-local) = ns*16+nh, row(l) = mg*16 + qd*4 + r
        const int colbase = s * BI + ih * 64;
        #pragma unroll
        for (int r = 0; r < 4; ++r) {
            const int row = mg * 16 + qd * 4 + r;
            const float* t1r = t1p + (size_t)row * ND1 + colbase + nh;
            #pragma unroll
            for (int ns = 0; ns < 4; ++ns)
                ps[r] += acc[ns][r] * t1r[ns * 16];
        }
    }

    // ---- final reduce across the 16 nh-lanes of each quad; 2 atomics per out row
    #pragma unroll
    for (int r = 0; r < 4; ++r) {
        float v = ps[r];
        v += __shfl_xor(v, 1);
        v += __shfl_xor(v, 2);
        v += __shfl_xor(v, 4);
        v += __shfl_xor(v, 8);
        if (nh == 0) atomicAdd(&out[b * NL + mg * 16 + qd * 4 + r], v);
    }
}

extern "C" void kernel_launch(void* const* d_in, const int* in_sizes, int n_in,
                              void* d_out, int out_size, void* d_ws, size_t ws_size,
                              hipStream_t stream)
{
    const float* t1  = (const float*)d_in[0];
    const float* t2  = (const float*)d_in[1];
    const int* pidx  = (const int*)d_in[2];
    const float* wgt = (const float*)d_in[3];
    float* out = (float*)d_out;

    hipMemsetAsync(out, 0, (size_t)out_size * sizeof(float), stream);
    pdot_kernel<<<dim3(NB), dim3(1024), 0, stream>>>(t1, t2, pidx, wgt, out);
}